// Round 2
// baseline (1280.835 us; speedup 1.0000x reference)
//
#include <hip/hip_runtime.h>
#include <hip/hip_bf16.h>
#include <math.h>

#define N_TOK 2048
#define DIM   1024
#define NE    16
#define NH    2048
#define NO    1024

typedef __attribute__((ext_vector_type(8))) short short8;
typedef __attribute__((ext_vector_type(4))) float f32x4;

__device__ __forceinline__ unsigned short f2bf(float f) {
  union { float f; unsigned u; } v; v.f = f;
  unsigned r = v.u + 0x7FFFu + ((v.u >> 16) & 1u);  // round-to-nearest-even
  return (unsigned short)(r >> 16);
}

__device__ __forceinline__ short8 pack8(float4 a, float4 b) {
  short8 r;
  r[0] = (short)f2bf(a.x); r[1] = (short)f2bf(a.y);
  r[2] = (short)f2bf(a.z); r[3] = (short)f2bf(a.w);
  r[4] = (short)f2bf(b.x); r[5] = (short)f2bf(b.y);
  r[6] = (short)f2bf(b.z); r[7] = (short)f2bf(b.w);
  return r;
}

// ---------------- Router: fp32 in, double accum, top-2 + renorm ----------------
__global__ __launch_bounds__(256) void router_kernel(
    const float* __restrict__ z, const float* __restrict__ rw,
    const float* __restrict__ rb, int* __restrict__ counts,
    int* __restrict__ list, float* __restrict__ tkw) {
  const int n = blockIdx.x;
  const int t = threadIdx.x;
  const int e = t >> 4, sub = t & 15;          // 16 threads per expert
  const float* zr = z + (size_t)n * DIM;
  const float* wr = rw + (size_t)e * DIM;
  double acc = 0.0;
#pragma unroll
  for (int i = 0; i < 16; ++i) {
    const int d = i * 64 + sub * 4;
    const float4 zv = *(const float4*)(zr + d);
    const float4 wv = *(const float4*)(wr + d);
    acc += (double)zv.x * wv.x + (double)zv.y * wv.y
         + (double)zv.z * wv.z + (double)zv.w * wv.w;
  }
  acc += __shfl_xor(acc, 8, 16);
  acc += __shfl_xor(acc, 4, 16);
  acc += __shfl_xor(acc, 2, 16);
  acc += __shfl_xor(acc, 1, 16);
  __shared__ double logits[NE];
  if (sub == 0) logits[e] = acc + (double)rb[e];
  __syncthreads();
  if (t == 0) {
    int i0 = -1, i1 = -1; double v0 = -1e300, v1 = -1e300;
    for (int i = 0; i < NE; ++i) {          // strict > : ties pick lowest index (matches lax.top_k)
      const double v = logits[i];
      if (v > v0) { v1 = v0; i1 = i0; v0 = v; i0 = i; }
      else if (v > v1) { v1 = v; i1 = i; }
    }
    const double w0 = 1.0 / (1.0 + exp(v1 - v0));   // p0/(p0+p1), softmax Z cancels
    tkw[n * 2 + 0] = (float)w0;
    tkw[n * 2 + 1] = (float)(1.0 - w0);
    const int p0 = atomicAdd(&counts[i0], 1); list[i0 * N_TOK + p0] = n * 2;
    const int p1 = atomicAdd(&counts[i1], 1); list[i1 * N_TOK + p1] = n * 2 + 1;
  }
}

// ---------------- GEMM1: h[slot] = gelu(z[tok] @ w1[e]^T + b1[e]) -> bf16 ----------------
#define BM 128
#define BN 128
#define BK 64
#define LDK 72   // stride 144B: frag reads 2-way (free); 16B-store rows cover all 32 banks

__global__ __launch_bounds__(256, 2) void gemm1_kernel(
    const float* __restrict__ z, const float* __restrict__ w1,
    const float* __restrict__ b1, const int* __restrict__ counts,
    const int* __restrict__ list, unsigned short* __restrict__ h) {
  const int bid = blockIdx.x;
  const int e  = bid >> 8;          // 16 nt * 16 mt per expert
  const int nt = (bid >> 4) & 15;
  const int mt = bid & 15;
  const int ne = counts[e];
  if (mt * BM >= ne) return;
  const int t = threadIdx.x;

  __shared__ unsigned short As[BM][LDK];
  __shared__ unsigned short Bs[BN][LDK];
  __shared__ int ent[BM];
  if (t < BM) {
    const int idx = mt * BM + t;
    ent[t] = (idx < ne) ? list[e * N_TOK + idx] : -1;
  }
  __syncthreads();

  const int lane = t & 63, wave = t >> 6;
  const int wm = (wave & 1) * 64, wn = (wave >> 1) * 64;
  const int l15 = lane & 15, q8 = (lane >> 4) * 8;

  f32x4 acc[4][4];
#pragma unroll
  for (int i = 0; i < 4; ++i)
#pragma unroll
    for (int j = 0; j < 4; ++j) acc[i][j] = (f32x4){0.f, 0.f, 0.f, 0.f};

  // staging: thread -> (row8 + p*32, col8..col8+7); 16B b128 LDS store, conflict-free
  const int row8 = t >> 3;          // 0..31
  const int col8 = (t & 7) * 8;     // 0,8,...,56

  const float* aR[4];
  const float* bR[4];
  const float* bbase = w1 + ((size_t)e * NH + (size_t)nt * BN) * DIM;
#pragma unroll
  for (int p = 0; p < 4; ++p) {
    const int row = row8 + p * 32;
    const int en = ent[row];
    aR[p] = z + (size_t)(en >= 0 ? (en >> 1) : 0) * DIM + col8;
    bR[p] = bbase + (size_t)row * DIM + col8;
  }

  float4 va[4][2], vb[4][2];
  // prologue loads (all issued back-to-back, no waits)
#pragma unroll
  for (int p = 0; p < 4; ++p) { va[p][0] = *(const float4*)(aR[p]); va[p][1] = *(const float4*)(aR[p] + 4); }
#pragma unroll
  for (int p = 0; p < 4; ++p) { vb[p][0] = *(const float4*)(bR[p]); vb[p][1] = *(const float4*)(bR[p] + 4); }

  for (int k0 = 0; k0 < DIM; k0 += BK) {
    // convert + store current regs to LDS (single vmcnt wait here)
#pragma unroll
    for (int p = 0; p < 4; ++p)
      *(short8*)&As[row8 + p * 32][col8] = pack8(va[p][0], va[p][1]);
#pragma unroll
    for (int p = 0; p < 4; ++p)
      *(short8*)&Bs[row8 + p * 32][col8] = pack8(vb[p][0], vb[p][1]);
    __syncthreads();
    // issue next tile's loads before MFMA: latency hides behind compute+barrier
    if (k0 + BK < DIM) {
      const int kn = k0 + BK;
#pragma unroll
      for (int p = 0; p < 4; ++p) { va[p][0] = *(const float4*)(aR[p] + kn); va[p][1] = *(const float4*)(aR[p] + kn + 4); }
#pragma unroll
      for (int p = 0; p < 4; ++p) { vb[p][0] = *(const float4*)(bR[p] + kn); vb[p][1] = *(const float4*)(bR[p] + kn + 4); }
    }
#pragma unroll
    for (int kk = 0; kk < BK; kk += 32) {
      short8 a[4], b[4];
#pragma unroll
      for (int i = 0; i < 4; ++i) a[i] = *(const short8*)&As[wm + i * 16 + l15][kk + q8];
#pragma unroll
      for (int j = 0; j < 4; ++j) b[j] = *(const short8*)&Bs[wn + j * 16 + l15][kk + q8];
#pragma unroll
      for (int i = 0; i < 4; ++i)
#pragma unroll
        for (int j = 0; j < 4; ++j)
          acc[i][j] = __builtin_amdgcn_mfma_f32_16x16x32_bf16(a[i], b[j], acc[i][j], 0, 0, 0);
    }
    __syncthreads();
  }

  const int r4 = (lane >> 4) * 4;   // C/D: col=lane&15, row=(lane>>4)*4+reg
#pragma unroll
  for (int i = 0; i < 4; ++i) {
#pragma unroll
    for (int reg = 0; reg < 4; ++reg) {
      const int row = wm + i * 16 + r4 + reg;
      const int en = ent[row];
      if (en < 0) continue;
      unsigned short* hrow = h + (size_t)en * NH;
#pragma unroll
      for (int j = 0; j < 4; ++j) {
        const int col = nt * BN + wn + j * 16 + l15;
        float v = acc[i][j][reg] + b1[e * NH + col];
        v = 0.5f * v * (1.0f + erff(v * 0.70710678118654752f));   // exact gelu
        hrow[col] = f2bf(v);
      }
    }
  }
}

// ---------------- GEMM2: contrib[slot] = h[slot] @ w2[e]^T + b2[e] (fp32) ----------------
// BN2=64: 512 active blocks (2/CU) for MLP; extra h re-reads land in L3 (16MB << 256MB)
#define BN2 64

__global__ __launch_bounds__(256, 2) void gemm2_kernel(
    const unsigned short* __restrict__ h, const float* __restrict__ w2,
    const float* __restrict__ b2, const int* __restrict__ counts,
    const int* __restrict__ list, float* __restrict__ contrib) {
  const int bid = blockIdx.x;
  const int e  = bid >> 8;          // 16 nt * 16 mt per expert
  const int nt = (bid >> 4) & 15;
  const int mt = bid & 15;
  const int ne = counts[e];
  if (mt * BM >= ne) return;
  const int t = threadIdx.x;

  __shared__ unsigned short As[BM][LDK];
  __shared__ unsigned short Bs[BN2][LDK];
  __shared__ int ent[BM];
  if (t < BM) {
    const int idx = mt * BM + t;
    ent[t] = (idx < ne) ? list[e * N_TOK + idx] : -1;
  }
  __syncthreads();

  const int lane = t & 63, wave = t >> 6;
  const int wm = (wave & 1) * 64, wn = (wave >> 1) * 32;   // wave tile 64x32
  const int l15 = lane & 15, q8 = (lane >> 4) * 8;

  f32x4 acc[4][2];
#pragma unroll
  for (int i = 0; i < 4; ++i)
#pragma unroll
    for (int j = 0; j < 2; ++j) acc[i][j] = (f32x4){0.f, 0.f, 0.f, 0.f};

  const int row8 = t >> 3;          // 0..31
  const int col8 = (t & 7) * 8;

  // A: bf16 passthrough (one 16B load per pass, 4 passes of 32 rows)
  const unsigned short* aR[4];
#pragma unroll
  for (int p = 0; p < 4; ++p) {
    const int en = ent[row8 + p * 32];
    aR[p] = h + (size_t)(en >= 0 ? en : 0) * NH + col8;
  }
  // B: fp32 w2 -> bf16 (2 passes of 32 rows)
  const float* bR[2];
  const float* bbase = w2 + ((size_t)e * NO + (size_t)nt * BN2) * NH;
#pragma unroll
  for (int p = 0; p < 2; ++p) bR[p] = bbase + (size_t)(row8 + p * 32) * NH + col8;

  float4 va[4], vb[2][2];
#pragma unroll
  for (int p = 0; p < 4; ++p) va[p] = *(const float4*)(aR[p]);
#pragma unroll
  for (int p = 0; p < 2; ++p) { vb[p][0] = *(const float4*)(bR[p]); vb[p][1] = *(const float4*)(bR[p] + 4); }

  for (int k0 = 0; k0 < NH; k0 += BK) {
#pragma unroll
    for (int p = 0; p < 4; ++p)
      *(float4*)&As[row8 + p * 32][col8] = va[p];        // raw 8 bf16
#pragma unroll
    for (int p = 0; p < 2; ++p)
      *(short8*)&Bs[row8 + p * 32][col8] = pack8(vb[p][0], vb[p][1]);
    __syncthreads();
    if (k0 + BK < NH) {
      const int kn = k0 + BK;
#pragma unroll
      for (int p = 0; p < 4; ++p) va[p] = *(const float4*)(aR[p] + kn);
#pragma unroll
      for (int p = 0; p < 2; ++p) { vb[p][0] = *(const float4*)(bR[p] + kn); vb[p][1] = *(const float4*)(bR[p] + kn + 4); }
    }
#pragma unroll
    for (int kk = 0; kk < BK; kk += 32) {
      short8 a[4], b[2];
#pragma unroll
      for (int i = 0; i < 4; ++i) a[i] = *(const short8*)&As[wm + i * 16 + l15][kk + q8];
#pragma unroll
      for (int j = 0; j < 2; ++j) b[j] = *(const short8*)&Bs[wn + j * 16 + l15][kk + q8];
#pragma unroll
      for (int i = 0; i < 4; ++i)
#pragma unroll
        for (int j = 0; j < 2; ++j)
          acc[i][j] = __builtin_amdgcn_mfma_f32_16x16x32_bf16(a[i], b[j], acc[i][j], 0, 0, 0);
    }
    __syncthreads();
  }

  const int r4 = (lane >> 4) * 4;
#pragma unroll
  for (int i = 0; i < 4; ++i) {
#pragma unroll
    for (int reg = 0; reg < 4; ++reg) {
      const int row = wm + i * 16 + r4 + reg;
      const int en = ent[row];
      if (en < 0) continue;
      float* crow = contrib + (size_t)en * NO;
#pragma unroll
      for (int j = 0; j < 2; ++j) {
        const int col = nt * BN2 + wn + j * 16 + l15;
        crow[col] = acc[i][j][reg] + b2[e * NO + col];
      }
    }
  }
}

// ---------------- Combine: out[n] = w0*contrib[2n] + w1*contrib[2n+1] ----------------
__global__ __launch_bounds__(256) void combine_kernel(
    const float* __restrict__ contrib, const float* __restrict__ tkw,
    float* __restrict__ out) {
  const int gid = blockIdx.x * 256 + threadIdx.x;   // N_TOK * (NO/4) threads
  const int n = gid >> 8;
  const int c = (gid & 255) * 4;
  const float w0 = tkw[n * 2], w1 = tkw[n * 2 + 1];
  const float4 a = *(const float4*)(contrib + (size_t)(n * 2) * NO + c);
  const float4 b = *(const float4*)(contrib + (size_t)(n * 2 + 1) * NO + c);
  float4 o;
  o.x = w0 * a.x + w1 * b.x; o.y = w0 * a.y + w1 * b.y;
  o.z = w0 * a.z + w1 * b.z; o.w = w0 * a.w + w1 * b.w;
  *(float4*)(out + (size_t)n * NO + c) = o;
}

extern "C" void kernel_launch(void* const* d_in, const int* in_sizes, int n_in,
                              void* d_out, int out_size, void* d_ws, size_t ws_size,
                              hipStream_t stream) {
  const float* z  = (const float*)d_in[0];
  const float* rw = (const float*)d_in[1];
  const float* rb = (const float*)d_in[2];
  const float* w1 = (const float*)d_in[3];
  const float* b1 = (const float*)d_in[4];
  const float* w2 = (const float*)d_in[5];
  const float* b2 = (const float*)d_in[6];
  float* out = (float*)d_out;

  char* ws = (char*)d_ws;
  int*   counts = (int*)ws;                                   // 64 B (zeroed below)
  int*   list   = (int*)(ws + 256);                           // 16*2048*4 = 128 KB
  float* tkw    = (float*)(ws + 256 + 131072);                // 16 KB
  unsigned short* h = (unsigned short*)(ws + 262144);         // 4096*2048 bf16 = 16 MB
  float* contrib = (float*)(ws + 262144 + 16777216);          // 4096*1024 f32 = 16 MB

  hipMemsetAsync(counts, 0, NE * sizeof(int), stream);
  router_kernel<<<N_TOK, 256, 0, stream>>>(z, rw, rb, counts, list, tkw);
  gemm1_kernel<<<NE * 16 * 16, 256, 0, stream>>>(z, w1, b1, counts, list, h);
  gemm2_kernel<<<NE * 16 * 16, 256, 0, stream>>>(h, w2, b2, counts, list, contrib);
  combine_kernel<<<(N_TOK * (NO / 4)) / 256, 256, 0, stream>>>(contrib, tkw, out);
}

// Round 3
// 507.435 us; speedup vs baseline: 2.5241x; 2.5241x over previous
//
#include <hip/hip_runtime.h>
#include <hip/hip_bf16.h>
#include <math.h>

#define N_TOK 2048
#define DIM   1024
#define NE    16
#define NH    2048
#define NO    1024

typedef __attribute__((ext_vector_type(8))) short short8;
typedef __attribute__((ext_vector_type(4))) float f32x4;

__device__ __forceinline__ unsigned short f2bf(float f) {
  union { float f; unsigned u; } v; v.f = f;
  unsigned r = v.u + 0x7FFFu + ((v.u >> 16) & 1u);  // round-to-nearest-even
  return (unsigned short)(r >> 16);
}

__device__ __forceinline__ short8 pack8(float4 a, float4 b) {
  short8 r;
  r[0] = (short)f2bf(a.x); r[1] = (short)f2bf(a.y);
  r[2] = (short)f2bf(a.z); r[3] = (short)f2bf(a.w);
  r[4] = (short)f2bf(b.x); r[5] = (short)f2bf(b.y);
  r[6] = (short)f2bf(b.z); r[7] = (short)f2bf(b.w);
  return r;
}

// ---------------- Router: fp32 in, double accum, top-2 + renorm ----------------
__global__ __launch_bounds__(256) void router_kernel(
    const float* __restrict__ z, const float* __restrict__ rw,
    const float* __restrict__ rb, int* __restrict__ counts,
    int* __restrict__ list, float* __restrict__ tkw) {
  const int n = blockIdx.x;
  const int t = threadIdx.x;
  const int e = t >> 4, sub = t & 15;          // 16 threads per expert
  const float* zr = z + (size_t)n * DIM;
  const float* wr = rw + (size_t)e * DIM;
  double acc = 0.0;
#pragma unroll
  for (int i = 0; i < 16; ++i) {
    const int d = i * 64 + sub * 4;
    const float4 zv = *(const float4*)(zr + d);
    const float4 wv = *(const float4*)(wr + d);
    acc += (double)zv.x * wv.x + (double)zv.y * wv.y
         + (double)zv.z * wv.z + (double)zv.w * wv.w;
  }
  acc += __shfl_xor(acc, 8, 16);
  acc += __shfl_xor(acc, 4, 16);
  acc += __shfl_xor(acc, 2, 16);
  acc += __shfl_xor(acc, 1, 16);
  __shared__ double logits[NE];
  if (sub == 0) logits[e] = acc + (double)rb[e];
  __syncthreads();
  if (t == 0) {
    int i0 = -1, i1 = -1; double v0 = -1e300, v1 = -1e300;
    for (int i = 0; i < NE; ++i) {          // strict > : ties pick lowest index (matches lax.top_k)
      const double v = logits[i];
      if (v > v0) { v1 = v0; i1 = i0; v0 = v; i0 = i; }
      else if (v > v1) { v1 = v; i1 = i; }
    }
    const double w0 = 1.0 / (1.0 + exp(v1 - v0));   // p0/(p0+p1), softmax Z cancels
    tkw[n * 2 + 0] = (float)w0;
    tkw[n * 2 + 1] = (float)(1.0 - w0);
    const int p0 = atomicAdd(&counts[i0], 1); list[i0 * N_TOK + p0] = n * 2;
    const int p1 = atomicAdd(&counts[i1], 1); list[i1 * N_TOK + p1] = n * 2 + 1;
  }
}

// ---------------- GEMM1: h[slot] = gelu(z[tok] @ w1[e]^T + b1[e]) -> bf16 ----------------
// BM=128, BN=64, BK=64. Grid is mt-MAJOR: active blocks (mt<~2) are a
// contiguous bid range -> spread round-robin over all XCDs/CUs.
#define BM 128
#define BN 64
#define BK 64
#define LDK 72
#define NNT1 (NH / BN)   // 32 n-tiles for gemm1
#define NNT2 (NO / BN)   // 16 n-tiles for gemm2

__global__ __launch_bounds__(256, 4) void gemm1_kernel(
    const float* __restrict__ z, const float* __restrict__ w1,
    const float* __restrict__ b1, const int* __restrict__ counts,
    const int* __restrict__ list, unsigned short* __restrict__ h) {
  const int bid = blockIdx.x;
  const int mt  = bid / (NE * NNT1);       // MAJOR: active mt levels contiguous
  const int rem = bid - mt * (NE * NNT1);
  const int e   = rem >> 5;
  const int nt  = rem & 31;
  const int ne = counts[e];
  if (mt * BM >= ne) return;
  const int t = threadIdx.x;

  __shared__ unsigned short As[BM][LDK];
  __shared__ unsigned short Bs[BN][LDK];
  __shared__ int ent[BM];
  if (t < BM) {
    const int idx = mt * BM + t;
    ent[t] = (idx < ne) ? list[e * N_TOK + idx] : -1;
  }
  __syncthreads();

  const int lane = t & 63, wave = t >> 6;
  const int wm = (wave & 1) * 64, wn = (wave >> 1) * 32;   // 64x32 wave tile
  const int l15 = lane & 15, q8 = (lane >> 4) * 8;

  f32x4 acc[4][2];
#pragma unroll
  for (int i = 0; i < 4; ++i)
#pragma unroll
    for (int j = 0; j < 2; ++j) acc[i][j] = (f32x4){0.f, 0.f, 0.f, 0.f};

  const int row8 = t >> 3;          // 0..31
  const int col8 = (t & 7) * 8;     // 0,8,...,56

  const float* aR[4];
  const float* bR[2];
  const float* bbase = w1 + ((size_t)e * NH + (size_t)nt * BN) * DIM;
#pragma unroll
  for (int p = 0; p < 4; ++p) {
    const int en = ent[row8 + p * 32];
    aR[p] = z + (size_t)(en >= 0 ? (en >> 1) : 0) * DIM + col8;
  }
#pragma unroll
  for (int p = 0; p < 2; ++p) bR[p] = bbase + (size_t)(row8 + p * 32) * DIM + col8;

  float4 va[4][2], vb[2][2];
#pragma unroll
  for (int p = 0; p < 4; ++p) { va[p][0] = *(const float4*)(aR[p]); va[p][1] = *(const float4*)(aR[p] + 4); }
#pragma unroll
  for (int p = 0; p < 2; ++p) { vb[p][0] = *(const float4*)(bR[p]); vb[p][1] = *(const float4*)(bR[p] + 4); }

  for (int k0 = 0; k0 < DIM; k0 += BK) {
#pragma unroll
    for (int p = 0; p < 4; ++p)
      *(short8*)&As[row8 + p * 32][col8] = pack8(va[p][0], va[p][1]);
#pragma unroll
    for (int p = 0; p < 2; ++p)
      *(short8*)&Bs[row8 + p * 32][col8] = pack8(vb[p][0], vb[p][1]);
    __syncthreads();
    if (k0 + BK < DIM) {
      const int kn = k0 + BK;
#pragma unroll
      for (int p = 0; p < 4; ++p) { va[p][0] = *(const float4*)(aR[p] + kn); va[p][1] = *(const float4*)(aR[p] + kn + 4); }
#pragma unroll
      for (int p = 0; p < 2; ++p) { vb[p][0] = *(const float4*)(bR[p] + kn); vb[p][1] = *(const float4*)(bR[p] + kn + 4); }
    }
#pragma unroll
    for (int kk = 0; kk < BK; kk += 32) {
      short8 a[4], b[2];
#pragma unroll
      for (int i = 0; i < 4; ++i) a[i] = *(const short8*)&As[wm + i * 16 + l15][kk + q8];
#pragma unroll
      for (int j = 0; j < 2; ++j) b[j] = *(const short8*)&Bs[wn + j * 16 + l15][kk + q8];
#pragma unroll
      for (int i = 0; i < 4; ++i)
#pragma unroll
        for (int j = 0; j < 2; ++j)
          acc[i][j] = __builtin_amdgcn_mfma_f32_16x16x32_bf16(a[i], b[j], acc[i][j], 0, 0, 0);
    }
    __syncthreads();
  }

  const int r4 = (lane >> 4) * 4;   // C/D: col=lane&15, row=(lane>>4)*4+reg
#pragma unroll
  for (int i = 0; i < 4; ++i) {
#pragma unroll
    for (int reg = 0; reg < 4; ++reg) {
      const int row = wm + i * 16 + r4 + reg;
      const int en = ent[row];
      if (en < 0) continue;
      unsigned short* hrow = h + (size_t)en * NH;
#pragma unroll
      for (int j = 0; j < 2; ++j) {
        const int col = nt * BN + wn + j * 16 + l15;
        float v = acc[i][j][reg] + b1[e * NH + col];
        v = 0.5f * v * (1.0f + erff(v * 0.70710678118654752f));   // exact gelu
        hrow[col] = f2bf(v);
      }
    }
  }
}

// ---------------- GEMM2: contrib[slot] = h[slot] @ w2[e]^T + b2[e] (fp32) ----------------
__global__ __launch_bounds__(256, 4) void gemm2_kernel(
    const unsigned short* __restrict__ h, const float* __restrict__ w2,
    const float* __restrict__ b2, const int* __restrict__ counts,
    const int* __restrict__ list, float* __restrict__ contrib) {
  const int bid = blockIdx.x;
  const int mt  = bid >> 8;                // MAJOR
  const int e   = (bid >> 4) & 15;
  const int nt  = bid & 15;
  const int ne = counts[e];
  if (mt * BM >= ne) return;
  const int t = threadIdx.x;

  __shared__ unsigned short As[BM][LDK];
  __shared__ unsigned short Bs[BN][LDK];
  __shared__ int ent[BM];
  if (t < BM) {
    const int idx = mt * BM + t;
    ent[t] = (idx < ne) ? list[e * N_TOK + idx] : -1;
  }
  __syncthreads();

  const int lane = t & 63, wave = t >> 6;
  const int wm = (wave & 1) * 64, wn = (wave >> 1) * 32;   // 64x32 wave tile
  const int l15 = lane & 15, q8 = (lane >> 4) * 8;

  f32x4 acc[4][2];
#pragma unroll
  for (int i = 0; i < 4; ++i)
#pragma unroll
    for (int j = 0; j < 2; ++j) acc[i][j] = (f32x4){0.f, 0.f, 0.f, 0.f};

  const int row8 = t >> 3;          // 0..31
  const int col8 = (t & 7) * 8;

  // A: bf16 passthrough (16B per pass, 4 passes of 32 rows)
  const unsigned short* aR[4];
#pragma unroll
  for (int p = 0; p < 4; ++p) {
    const int en = ent[row8 + p * 32];
    aR[p] = h + (size_t)(en >= 0 ? en : 0) * NH + col8;
  }
  // B: fp32 w2 -> bf16 (2 passes of 32 rows)
  const float* bR[2];
  const float* bbase = w2 + ((size_t)e * NO + (size_t)nt * BN) * NH;
#pragma unroll
  for (int p = 0; p < 2; ++p) bR[p] = bbase + (size_t)(row8 + p * 32) * NH + col8;

  float4 va[4], vb[2][2];
#pragma unroll
  for (int p = 0; p < 4; ++p) va[p] = *(const float4*)(aR[p]);
#pragma unroll
  for (int p = 0; p < 2; ++p) { vb[p][0] = *(const float4*)(bR[p]); vb[p][1] = *(const float4*)(bR[p] + 4); }

  for (int k0 = 0; k0 < NH; k0 += BK) {
#pragma unroll
    for (int p = 0; p < 4; ++p)
      *(float4*)&As[row8 + p * 32][col8] = va[p];        // raw 8 bf16
#pragma unroll
    for (int p = 0; p < 2; ++p)
      *(short8*)&Bs[row8 + p * 32][col8] = pack8(vb[p][0], vb[p][1]);
    __syncthreads();
    if (k0 + BK < NH) {
      const int kn = k0 + BK;
#pragma unroll
      for (int p = 0; p < 4; ++p) va[p] = *(const float4*)(aR[p] + kn);
#pragma unroll
      for (int p = 0; p < 2; ++p) { vb[p][0] = *(const float4*)(bR[p] + kn); vb[p][1] = *(const float4*)(bR[p] + kn + 4); }
    }
#pragma unroll
    for (int kk = 0; kk < BK; kk += 32) {
      short8 a[4], b[2];
#pragma unroll
      for (int i = 0; i < 4; ++i) a[i] = *(const short8*)&As[wm + i * 16 + l15][kk + q8];
#pragma unroll
      for (int j = 0; j < 2; ++j) b[j] = *(const short8*)&Bs[wn + j * 16 + l15][kk + q8];
#pragma unroll
      for (int i = 0; i < 4; ++i)
#pragma unroll
        for (int j = 0; j < 2; ++j)
          acc[i][j] = __builtin_amdgcn_mfma_f32_16x16x32_bf16(a[i], b[j], acc[i][j], 0, 0, 0);
    }
    __syncthreads();
  }

  const int r4 = (lane >> 4) * 4;
#pragma unroll
  for (int i = 0; i < 4; ++i) {
#pragma unroll
    for (int reg = 0; reg < 4; ++reg) {
      const int row = wm + i * 16 + r4 + reg;
      const int en = ent[row];
      if (en < 0) continue;
      float* crow = contrib + (size_t)en * NO;
#pragma unroll
      for (int j = 0; j < 2; ++j) {
        const int col = nt * BN + wn + j * 16 + l15;
        crow[col] = acc[i][j][reg] + b2[e * NO + col];
      }
    }
  }
}

// ---------------- Combine: out[n] = w0*contrib[2n] + w1*contrib[2n+1] ----------------
__global__ __launch_bounds__(256) void combine_kernel(
    const float* __restrict__ contrib, const float* __restrict__ tkw,
    float* __restrict__ out) {
  const int gid = blockIdx.x * 256 + threadIdx.x;   // N_TOK * (NO/4) threads
  const int n = gid >> 8;
  const int c = (gid & 255) * 4;
  const float w0 = tkw[n * 2], w1 = tkw[n * 2 + 1];
  const float4 a = *(const float4*)(contrib + (size_t)(n * 2) * NO + c);
  const float4 b = *(const float4*)(contrib + (size_t)(n * 2 + 1) * NO + c);
  float4 o;
  o.x = w0 * a.x + w1 * b.x; o.y = w0 * a.y + w1 * b.y;
  o.z = w0 * a.z + w1 * b.z; o.w = w0 * a.w + w1 * b.w;
  *(float4*)(out + (size_t)n * NO + c) = o;
}

extern "C" void kernel_launch(void* const* d_in, const int* in_sizes, int n_in,
                              void* d_out, int out_size, void* d_ws, size_t ws_size,
                              hipStream_t stream) {
  const float* z  = (const float*)d_in[0];
  const float* rw = (const float*)d_in[1];
  const float* rb = (const float*)d_in[2];
  const float* w1 = (const float*)d_in[3];
  const float* b1 = (const float*)d_in[4];
  const float* w2 = (const float*)d_in[5];
  const float* b2 = (const float*)d_in[6];
  float* out = (float*)d_out;

  char* ws = (char*)d_ws;
  int*   counts = (int*)ws;                                   // 64 B (zeroed below)
  int*   list   = (int*)(ws + 256);                           // 16*2048*4 = 128 KB
  float* tkw    = (float*)(ws + 256 + 131072);                // 16 KB
  unsigned short* h = (unsigned short*)(ws + 262144);         // 4096*2048 bf16 = 16 MB
  float* contrib = (float*)(ws + 262144 + 16777216);          // 4096*1024 f32 = 16 MB

  hipMemsetAsync(counts, 0, NE * sizeof(int), stream);
  router_kernel<<<N_TOK, 256, 0, stream>>>(z, rw, rb, counts, list, tkw);
  gemm1_kernel<<<16 * NE * NNT1, 256, 0, stream>>>(z, w1, b1, counts, list, h);
  gemm2_kernel<<<16 * NE * NNT2, 256, 0, stream>>>(h, w2, b2, counts, list, contrib);
  combine_kernel<<<(N_TOK * (NO / 4)) / 256, 256, 0, stream>>>(contrib, tkw, out);
}

// Round 4
// 497.402 us; speedup vs baseline: 2.5751x; 1.0202x over previous
//
#include <hip/hip_runtime.h>
#include <hip/hip_bf16.h>
#include <math.h>

#define N_TOK 2048
#define DIM   1024
#define NE    16
#define NH    2048
#define NO    1024

typedef __attribute__((ext_vector_type(8))) short short8;
typedef __attribute__((ext_vector_type(4))) float f32x4;

__device__ __forceinline__ unsigned short f2bf(float f) {
  union { float f; unsigned u; } v; v.f = f;
  unsigned r = v.u + 0x7FFFu + ((v.u >> 16) & 1u);  // round-to-nearest-even
  return (unsigned short)(r >> 16);
}

__device__ __forceinline__ short8 pack8(float4 a, float4 b) {
  short8 r;
  r[0] = (short)f2bf(a.x); r[1] = (short)f2bf(a.y);
  r[2] = (short)f2bf(a.z); r[3] = (short)f2bf(a.w);
  r[4] = (short)f2bf(b.x); r[5] = (short)f2bf(b.y);
  r[6] = (short)f2bf(b.z); r[7] = (short)f2bf(b.w);
  return r;
}

// LDS-only barrier: waits lgkmcnt(0) but leaves global loads (vmcnt) in flight,
// so prefetched tiles stream across iterations instead of draining per-iter.
// imm 0xC07F = vmcnt(63) expcnt(7) lgkmcnt(0) on gfx9-lineage encoding.
__device__ __forceinline__ void lds_barrier() {
  __builtin_amdgcn_s_waitcnt(0xC07F);
  __builtin_amdgcn_s_barrier();
}

// ---------------- Router: fp32 in, double accum, top-2 + renorm ----------------
__global__ __launch_bounds__(256) void router_kernel(
    const float* __restrict__ z, const float* __restrict__ rw,
    const float* __restrict__ rb, int* __restrict__ counts,
    int* __restrict__ list, float* __restrict__ tkw) {
  const int n = blockIdx.x;
  const int t = threadIdx.x;
  const int e = t >> 4, sub = t & 15;          // 16 threads per expert
  const float* zr = z + (size_t)n * DIM;
  const float* wr = rw + (size_t)e * DIM;
  double acc = 0.0;
#pragma unroll
  for (int i = 0; i < 16; ++i) {
    const int d = i * 64 + sub * 4;
    const float4 zv = *(const float4*)(zr + d);
    const float4 wv = *(const float4*)(wr + d);
    acc += (double)zv.x * wv.x + (double)zv.y * wv.y
         + (double)zv.z * wv.z + (double)zv.w * wv.w;
  }
  acc += __shfl_xor(acc, 8, 16);
  acc += __shfl_xor(acc, 4, 16);
  acc += __shfl_xor(acc, 2, 16);
  acc += __shfl_xor(acc, 1, 16);
  __shared__ double logits[NE];
  if (sub == 0) logits[e] = acc + (double)rb[e];
  __syncthreads();
  if (t == 0) {
    int i0 = -1, i1 = -1; double v0 = -1e300, v1 = -1e300;
    for (int i = 0; i < NE; ++i) {          // strict > : ties pick lowest index (matches lax.top_k)
      const double v = logits[i];
      if (v > v0) { v1 = v0; i1 = i0; v0 = v; i0 = i; }
      else if (v > v1) { v1 = v; i1 = i; }
    }
    const double w0 = 1.0 / (1.0 + exp(v1 - v0));   // p0/(p0+p1), softmax Z cancels
    tkw[n * 2 + 0] = (float)w0;
    tkw[n * 2 + 1] = (float)(1.0 - w0);
    const int p0 = atomicAdd(&counts[i0], 1); list[i0 * N_TOK + p0] = n * 2;
    const int p1 = atomicAdd(&counts[i1], 1); list[i1 * N_TOK + p1] = n * 2 + 1;
  }
}

#define BM 128
#define BN 64
#define BK 64
#define LDK 72
#define NNT1 (NH / BN)   // 32
#define NNT2 (NO / BN)   // 16

// XCD-pair decode: active mt∈{0,1} pairs of the same (e,nt) differ by bid 8
// -> same XCD (bid%8) -> L2 MSHR merges the duplicate weight fetch.
// nent = NE*NNT. bids [0, 2*nent): c=bid>>4, mt=(bid>>3)&1, r=bid&7, ent=c*8+r.
// stragglers mt>=2: bid = 2*nent + (mt-2)*nent + ent.
__device__ __forceinline__ void decode_bid(int bid, int nent, int& mt, int& ent) {
  if (bid < 2 * nent) {
    mt = (bid >> 3) & 1;
    ent = (bid >> 4) * 8 + (bid & 7);
  } else {
    const int t2 = bid - 2 * nent;
    mt = 2 + t2 / nent;
    ent = t2 - (mt - 2) * nent;
  }
}

// ---------------- GEMM1: h[slot] = gelu(z[tok] @ w1[e]^T + b1[e]) -> bf16 ----------------
__global__ __launch_bounds__(256, 4) void gemm1_kernel(
    const float* __restrict__ z, const float* __restrict__ w1,
    const float* __restrict__ b1, const int* __restrict__ counts,
    const int* __restrict__ list, unsigned short* __restrict__ h) {
  int mt, ent;
  decode_bid(blockIdx.x, NE * NNT1, mt, ent);
  const int e  = ent >> 5;
  const int nt = ent & 31;
  const int ne = counts[e];
  if (mt * BM >= ne) return;
  const int t = threadIdx.x;

  __shared__ unsigned short As[BM][LDK];
  __shared__ unsigned short Bs[BN][LDK];
  __shared__ int ent_s[BM];
  if (t < BM) {
    const int idx = mt * BM + t;
    ent_s[t] = (idx < ne) ? list[e * N_TOK + idx] : -1;
  }
  __syncthreads();

  const int lane = t & 63, wave = t >> 6;
  const int wm = (wave & 1) * 64, wn = (wave >> 1) * 32;   // 64x32 wave tile
  const int l15 = lane & 15, q8 = (lane >> 4) * 8;

  f32x4 acc[4][2];
#pragma unroll
  for (int i = 0; i < 4; ++i)
#pragma unroll
    for (int j = 0; j < 2; ++j) acc[i][j] = (f32x4){0.f, 0.f, 0.f, 0.f};

  const int row8 = t >> 3;          // 0..31
  const int col8 = (t & 7) * 8;     // 0,8,...,56

  const float* aR[4];
  const float* bR[2];
  const float* bbase = w1 + ((size_t)e * NH + (size_t)nt * BN) * DIM;
#pragma unroll
  for (int p = 0; p < 4; ++p) {
    const int en = ent_s[row8 + p * 32];
    aR[p] = z + (size_t)(en >= 0 ? (en >> 1) : 0) * DIM + col8;
  }
#pragma unroll
  for (int p = 0; p < 2; ++p) bR[p] = bbase + (size_t)(row8 + p * 32) * DIM + col8;

  float4 va[4][2], vb[2][2];
#pragma unroll
  for (int p = 0; p < 4; ++p) { va[p][0] = *(const float4*)(aR[p]); va[p][1] = *(const float4*)(aR[p] + 4); }
#pragma unroll
  for (int p = 0; p < 2; ++p) { vb[p][0] = *(const float4*)(bR[p]); vb[p][1] = *(const float4*)(bR[p] + 4); }

  for (int k0 = 0; k0 < DIM; k0 += BK) {
#pragma unroll
    for (int p = 0; p < 4; ++p)
      *(short8*)&As[row8 + p * 32][col8] = pack8(va[p][0], va[p][1]);
#pragma unroll
    for (int p = 0; p < 2; ++p)
      *(short8*)&Bs[row8 + p * 32][col8] = pack8(vb[p][0], vb[p][1]);
    lds_barrier();
    if (k0 + BK < DIM) {
      const int kn = k0 + BK;
#pragma unroll
      for (int p = 0; p < 4; ++p) { va[p][0] = *(const float4*)(aR[p] + kn); va[p][1] = *(const float4*)(aR[p] + kn + 4); }
#pragma unroll
      for (int p = 0; p < 2; ++p) { vb[p][0] = *(const float4*)(bR[p] + kn); vb[p][1] = *(const float4*)(bR[p] + kn + 4); }
    }
#pragma unroll
    for (int kk = 0; kk < BK; kk += 32) {
      short8 a[4], b[2];
#pragma unroll
      for (int i = 0; i < 4; ++i) a[i] = *(const short8*)&As[wm + i * 16 + l15][kk + q8];
#pragma unroll
      for (int j = 0; j < 2; ++j) b[j] = *(const short8*)&Bs[wn + j * 16 + l15][kk + q8];
#pragma unroll
      for (int i = 0; i < 4; ++i)
#pragma unroll
        for (int j = 0; j < 2; ++j)
          acc[i][j] = __builtin_amdgcn_mfma_f32_16x16x32_bf16(a[i], b[j], acc[i][j], 0, 0, 0);
    }
    lds_barrier();
  }

  const int r4 = (lane >> 4) * 4;   // C/D: col=lane&15, row=(lane>>4)*4+reg
#pragma unroll
  for (int i = 0; i < 4; ++i) {
#pragma unroll
    for (int reg = 0; reg < 4; ++reg) {
      const int row = wm + i * 16 + r4 + reg;
      const int en = ent_s[row];
      if (en < 0) continue;
      unsigned short* hrow = h + (size_t)en * NH;
#pragma unroll
      for (int j = 0; j < 2; ++j) {
        const int col = nt * BN + wn + j * 16 + l15;
        float v = acc[i][j][reg] + b1[e * NH + col];
        v = 0.5f * v * (1.0f + erff(v * 0.70710678118654752f));   // exact gelu
        hrow[col] = f2bf(v);
      }
    }
  }
}

// ---------------- GEMM2: contrib[slot] = h[slot] @ w2[e]^T + b2[e] (fp32) ----------------
__global__ __launch_bounds__(256, 4) void gemm2_kernel(
    const unsigned short* __restrict__ h, const float* __restrict__ w2,
    const float* __restrict__ b2, const int* __restrict__ counts,
    const int* __restrict__ list, float* __restrict__ contrib) {
  int mt, ent;
  decode_bid(blockIdx.x, NE * NNT2, mt, ent);
  const int e  = ent >> 4;
  const int nt = ent & 15;
  const int ne = counts[e];
  if (mt * BM >= ne) return;
  const int t = threadIdx.x;

  __shared__ unsigned short As[BM][LDK];
  __shared__ unsigned short Bs[BN][LDK];
  __shared__ int ent_s[BM];
  if (t < BM) {
    const int idx = mt * BM + t;
    ent_s[t] = (idx < ne) ? list[e * N_TOK + idx] : -1;
  }
  __syncthreads();

  const int lane = t & 63, wave = t >> 6;
  const int wm = (wave & 1) * 64, wn = (wave >> 1) * 32;   // 64x32 wave tile
  const int l15 = lane & 15, q8 = (lane >> 4) * 8;

  f32x4 acc[4][2];
#pragma unroll
  for (int i = 0; i < 4; ++i)
#pragma unroll
    for (int j = 0; j < 2; ++j) acc[i][j] = (f32x4){0.f, 0.f, 0.f, 0.f};

  const int row8 = t >> 3;          // 0..31
  const int col8 = (t & 7) * 8;

  // A: bf16 passthrough (16B per pass, 4 passes of 32 rows)
  const unsigned short* aR[4];
#pragma unroll
  for (int p = 0; p < 4; ++p) {
    const int en = ent_s[row8 + p * 32];
    aR[p] = h + (size_t)(en >= 0 ? en : 0) * NH + col8;
  }
  // B: fp32 w2 -> bf16 (2 passes of 32 rows)
  const float* bR[2];
  const float* bbase = w2 + ((size_t)e * NO + (size_t)nt * BN) * NH;
#pragma unroll
  for (int p = 0; p < 2; ++p) bR[p] = bbase + (size_t)(row8 + p * 32) * NH + col8;

  float4 va[4], vb[2][2];
#pragma unroll
  for (int p = 0; p < 4; ++p) va[p] = *(const float4*)(aR[p]);
#pragma unroll
  for (int p = 0; p < 2; ++p) { vb[p][0] = *(const float4*)(bR[p]); vb[p][1] = *(const float4*)(bR[p] + 4); }

  for (int k0 = 0; k0 < NH; k0 += BK) {
#pragma unroll
    for (int p = 0; p < 4; ++p)
      *(float4*)&As[row8 + p * 32][col8] = va[p];        // raw 8 bf16
#pragma unroll
    for (int p = 0; p < 2; ++p)
      *(short8*)&Bs[row8 + p * 32][col8] = pack8(vb[p][0], vb[p][1]);
    lds_barrier();
    if (k0 + BK < NH) {
      const int kn = k0 + BK;
#pragma unroll
      for (int p = 0; p < 4; ++p) va[p] = *(const float4*)(aR[p] + kn);
#pragma unroll
      for (int p = 0; p < 2; ++p) { vb[p][0] = *(const float4*)(bR[p] + kn); vb[p][1] = *(const float4*)(bR[p] + kn + 4); }
    }
#pragma unroll
    for (int kk = 0; kk < BK; kk += 32) {
      short8 a[4], b[2];
#pragma unroll
      for (int i = 0; i < 4; ++i) a[i] = *(const short8*)&As[wm + i * 16 + l15][kk + q8];
#pragma unroll
      for (int j = 0; j < 2; ++j) b[j] = *(const short8*)&Bs[wn + j * 16 + l15][kk + q8];
#pragma unroll
      for (int i = 0; i < 4; ++i)
#pragma unroll
        for (int j = 0; j < 2; ++j)
          acc[i][j] = __builtin_amdgcn_mfma_f32_16x16x32_bf16(a[i], b[j], acc[i][j], 0, 0, 0);
    }
    lds_barrier();
  }

  const int r4 = (lane >> 4) * 4;
#pragma unroll
  for (int i = 0; i < 4; ++i) {
#pragma unroll
    for (int reg = 0; reg < 4; ++reg) {
      const int row = wm + i * 16 + r4 + reg;
      const int en = ent_s[row];
      if (en < 0) continue;
      float* crow = contrib + (size_t)en * NO;
#pragma unroll
      for (int j = 0; j < 2; ++j) {
        const int col = nt * BN + wn + j * 16 + l15;
        crow[col] = acc[i][j][reg] + b2[e * NO + col];
      }
    }
  }
}

// ---------------- Combine: out[n] = w0*contrib[2n] + w1*contrib[2n+1] ----------------
__global__ __launch_bounds__(256) void combine_kernel(
    const float* __restrict__ contrib, const float* __restrict__ tkw,
    float* __restrict__ out) {
  const int gid = blockIdx.x * 256 + threadIdx.x;   // N_TOK * (NO/4) threads
  const int n = gid >> 8;
  const int c = (gid & 255) * 4;
  const float w0 = tkw[n * 2], w1 = tkw[n * 2 + 1];
  const float4 a = *(const float4*)(contrib + (size_t)(n * 2) * NO + c);
  const float4 b = *(const float4*)(contrib + (size_t)(n * 2 + 1) * NO + c);
  float4 o;
  o.x = w0 * a.x + w1 * b.x; o.y = w0 * a.y + w1 * b.y;
  o.z = w0 * a.z + w1 * b.z; o.w = w0 * a.w + w1 * b.w;
  *(float4*)(out + (size_t)n * NO + c) = o;
}

extern "C" void kernel_launch(void* const* d_in, const int* in_sizes, int n_in,
                              void* d_out, int out_size, void* d_ws, size_t ws_size,
                              hipStream_t stream) {
  const float* z  = (const float*)d_in[0];
  const float* rw = (const float*)d_in[1];
  const float* rb = (const float*)d_in[2];
  const float* w1 = (const float*)d_in[3];
  const float* b1 = (const float*)d_in[4];
  const float* w2 = (const float*)d_in[5];
  const float* b2 = (const float*)d_in[6];
  float* out = (float*)d_out;

  char* ws = (char*)d_ws;
  int*   counts = (int*)ws;                                   // 64 B (zeroed below)
  int*   list   = (int*)(ws + 256);                           // 128 KB
  float* tkw    = (float*)(ws + 256 + 131072);                // 16 KB
  unsigned short* h = (unsigned short*)(ws + 262144);         // 16 MB
  float* contrib = (float*)(ws + 262144 + 16777216);          // 16 MB

  hipMemsetAsync(counts, 0, NE * sizeof(int), stream);
  router_kernel<<<N_TOK, 256, 0, stream>>>(z, rw, rb, counts, list, tkw);
  gemm1_kernel<<<16 * NE * NNT1, 256, 0, stream>>>(z, w1, b1, counts, list, h);
  gemm2_kernel<<<16 * NE * NNT2, 256, 0, stream>>>(h, w2, b2, counts, list, contrib);
  combine_kernel<<<(N_TOK * (NO / 4)) / 256, 256, 0, stream>>>(contrib, tkw, out);
}

// Round 5
// 427.826 us; speedup vs baseline: 2.9938x; 1.1626x over previous
//
#include <hip/hip_runtime.h>
#include <hip/hip_bf16.h>
#include <math.h>

#define N_TOK 2048
#define DIM   1024
#define NE    16
#define NH    2048
#define NO    1024

typedef __attribute__((ext_vector_type(8))) short short8;
typedef __attribute__((ext_vector_type(4))) float f32x4;

__device__ __forceinline__ unsigned short f2bf(float f) {
  union { float f; unsigned u; } v; v.f = f;
  unsigned r = v.u + 0x7FFFu + ((v.u >> 16) & 1u);  // RNE
  return (unsigned short)(r >> 16);
}

__device__ __forceinline__ short8 pack8(float4 a, float4 b) {
  short8 r;
  r[0] = (short)f2bf(a.x); r[1] = (short)f2bf(a.y);
  r[2] = (short)f2bf(a.z); r[3] = (short)f2bf(a.w);
  r[4] = (short)f2bf(b.x); r[5] = (short)f2bf(b.y);
  r[6] = (short)f2bf(b.z); r[7] = (short)f2bf(b.w);
  return r;
}

__device__ __forceinline__ unsigned pkbf(float x, float y) {
  float2 f; f.x = x; f.y = y;
  __hip_bfloat162 b = __float22bfloat162_rn(f);     // v_cvt_pk_bf16_f32 (RNE)
  unsigned u; __builtin_memcpy(&u, &b, 4);
  return u;
}
__device__ __forceinline__ short8 cvt8(float4 a, float4 b) {
  union { short8 s; unsigned u[4]; } r;
  r.u[0] = pkbf(a.x, a.y); r.u[1] = pkbf(a.z, a.w);
  r.u[2] = pkbf(b.x, b.y); r.u[3] = pkbf(b.z, b.w);
  return r.s;
}

// async global->LDS, 16B/lane; LDS dest = wave-uniform base + lane*16 (m97/m104)
__device__ __forceinline__ void glds16(const void* g, void* l) {
  __builtin_amdgcn_global_load_lds(
      (const __attribute__((address_space(1))) void*)g,
      (__attribute__((address_space(3))) void*)l, 16, 0, 0);
}

// LDS-only barrier (lgkmcnt(0), vmcnt untouched) for the WAR edge after MFMA.
__device__ __forceinline__ void lds_barrier() {
  __builtin_amdgcn_s_waitcnt(0xC07F);
  __builtin_amdgcn_s_barrier();
}

// ---------------- Router: fp32 in, double accum, top-2 + renorm ----------------
__global__ __launch_bounds__(256) void router_kernel(
    const float* __restrict__ z, const float* __restrict__ rw,
    const float* __restrict__ rb, int* __restrict__ counts,
    int* __restrict__ list, float* __restrict__ tkw) {
  const int n = blockIdx.x;
  const int t = threadIdx.x;
  const int e = t >> 4, sub = t & 15;
  const float* zr = z + (size_t)n * DIM;
  const float* wr = rw + (size_t)e * DIM;
  double acc = 0.0;
#pragma unroll
  for (int i = 0; i < 16; ++i) {
    const int d = i * 64 + sub * 4;
    const float4 zv = *(const float4*)(zr + d);
    const float4 wv = *(const float4*)(wr + d);
    acc += (double)zv.x * wv.x + (double)zv.y * wv.y
         + (double)zv.z * wv.z + (double)zv.w * wv.w;
  }
  acc += __shfl_xor(acc, 8, 16);
  acc += __shfl_xor(acc, 4, 16);
  acc += __shfl_xor(acc, 2, 16);
  acc += __shfl_xor(acc, 1, 16);
  __shared__ double logits[NE];
  if (sub == 0) logits[e] = acc + (double)rb[e];
  __syncthreads();
  if (t == 0) {
    int i0 = -1, i1 = -1; double v0 = -1e300, v1 = -1e300;
    for (int i = 0; i < NE; ++i) {
      const double v = logits[i];
      if (v > v0) { v1 = v0; i1 = i0; v0 = v; i0 = i; }
      else if (v > v1) { v1 = v; i1 = i; }
    }
    const double w0 = 1.0 / (1.0 + exp(v1 - v0));
    tkw[n * 2 + 0] = (float)w0;
    tkw[n * 2 + 1] = (float)(1.0 - w0);
    const int p0 = atomicAdd(&counts[i0], 1); list[i0 * N_TOK + p0] = n * 2;
    const int p1 = atomicAdd(&counts[i1], 1); list[i1 * N_TOK + p1] = n * 2 + 1;
  }
}

// ---------------- z -> bf16 (once per call) ----------------
__global__ __launch_bounds__(256) void convert_z_kernel(
    const float* __restrict__ z, unsigned short* __restrict__ zbf) {
  const int i = (blockIdx.x * 256 + threadIdx.x) * 8;
  const float4 a = *(const float4*)(z + i);
  const float4 b = *(const float4*)(z + i + 4);
  *(short8*)(zbf + i) = pack8(a, b);
}

#define BM 128
#define BN 128
#define BK 64
#define NNT1 (NH / BN)   // 16
#define NNT2 (NO / BN)   // 8
#define MT_LEVELS 8

// mt-major (active mt contiguous) + XCD-pair: the two mt blocks of one (e,nt)
// differ by bid 8 -> same XCD -> L2 merges the duplicate weight fetch.
__device__ __forceinline__ void decode_bid(int bid, int nent, int& mt, int& ent) {
  if (bid < 2 * nent) {
    mt = (bid >> 3) & 1;
    ent = (bid >> 4) * 8 + (bid & 7);
  } else {
    const int t2 = bid - 2 * nent;
    mt = 2 + t2 / nent;
    ent = t2 - (mt - 2) * nent;
  }
}

// ---------------- GEMM1: h[slot] = gelu(zbf[tok] @ w1[e]^T + b1[e]) -> bf16 ----------------
__global__ __launch_bounds__(256, 2) void gemm1_kernel(
    const unsigned short* __restrict__ zbf, const float* __restrict__ w1,
    const float* __restrict__ b1, const int* __restrict__ counts,
    const int* __restrict__ list, unsigned short* __restrict__ h) {
  int mt, ent;
  decode_bid(blockIdx.x, NE * NNT1, mt, ent);
  const int e  = ent >> 4;
  const int nt = ent & 15;
  const int ne = counts[e];
  if (mt * BM >= ne) return;
  const int t = threadIdx.x;

  // A: bf16 [128 rows x 128 B], XOR-swizzled chunks. B: fp32 [128 rows x 256 B].
  __shared__ __align__(16) unsigned char As[BM * BK * 2];   // 16 KB
  __shared__ __align__(16) unsigned char Bs[BN * BK * 4];   // 32 KB
  __shared__ int ent_s[BM];
  if (t < BM) {
    const int idx = mt * BM + t;
    ent_s[t] = (idx < ne) ? list[e * N_TOK + idx] : -1;
  }
  __syncthreads();

  const int lane = t & 63, w = t >> 6;
  // staging pointers: A 4 chunks/wave (1KB each), B 8 chunks/wave
  const unsigned short* aP[4];
  const float* bP[8];
  unsigned char *aL[4], *bL[8];
  {
    const int l3 = lane >> 3, c7 = lane & 7;
#pragma unroll
    for (int p = 0; p < 4; ++p) {
      const int CI = w + 4 * p;
      const int R = 8 * CI + l3;
      const int c = c7 ^ (R & 7);
      const int en = ent_s[R];
      aP[p] = zbf + (size_t)(en >= 0 ? (en >> 1) : 0) * DIM + c * 8;
      aL[p] = As + CI * 1024;
    }
    const int l4 = lane >> 4, c15 = lane & 15;
    const float* bbase = w1 + ((size_t)e * NH + (size_t)nt * BN) * DIM;
#pragma unroll
    for (int q = 0; q < 8; ++q) {
      const int CI = w + 4 * q;
      const int R = 4 * CI + l4;
      const int c = c15 ^ (R & 15);
      bP[q] = bbase + (size_t)R * DIM + c * 4;
      bL[q] = Bs + CI * 1024;
    }
  }

  const int wm = (w & 1) * 64, wn = (w >> 1) * 64;
  const int l15 = lane & 15, quad = lane >> 4;

  f32x4 acc[4][4];
#pragma unroll
  for (int i = 0; i < 4; ++i)
#pragma unroll
    for (int j = 0; j < 4; ++j) acc[i][j] = (f32x4){0.f, 0.f, 0.f, 0.f};

  for (int k0 = 0; k0 < DIM; k0 += BK) {
#pragma unroll
    for (int p = 0; p < 4; ++p) glds16(aP[p] + k0, aL[p]);
#pragma unroll
    for (int q = 0; q < 8; ++q) glds16(bP[q] + k0, bL[q]);
    __syncthreads();          // vmcnt(0) drain -> LDS filled (m97 structure)
#pragma unroll
    for (int kk = 0; kk < BK; kk += 32) {
      short8 af[4], bfr[4];
#pragma unroll
      for (int i = 0; i < 4; ++i) {
        const int R = wm + i * 16 + l15;
        const int c0 = (kk >> 3) + quad;
        af[i] = *(const short8*)(As + R * 128 + ((c0 ^ (R & 7)) << 4));
      }
#pragma unroll
      for (int j = 0; j < 4; ++j) {
        const int R = wn + j * 16 + l15;
        const int c0 = (kk >> 2) + 2 * quad;
        const float4 f0 = *(const float4*)(Bs + R * 256 + ((c0 ^ (R & 15)) << 4));
        const float4 f1 = *(const float4*)(Bs + R * 256 + (((c0 + 1) ^ (R & 15)) << 4));
        bfr[j] = cvt8(f0, f1);
      }
#pragma unroll
      for (int i = 0; i < 4; ++i)
#pragma unroll
        for (int j = 0; j < 4; ++j)
          acc[i][j] = __builtin_amdgcn_mfma_f32_16x16x32_bf16(af[i], bfr[j], acc[i][j], 0, 0, 0);
    }
    lds_barrier();            // readers done before next fill (WAR)
  }

  const int r4 = quad * 4;    // C/D: col=lane&15, row=quad*4+reg
#pragma unroll
  for (int i = 0; i < 4; ++i) {
#pragma unroll
    for (int reg = 0; reg < 4; ++reg) {
      const int row = wm + i * 16 + r4 + reg;
      const int en = ent_s[row];
      if (en < 0) continue;
      unsigned short* hrow = h + (size_t)en * NH;
#pragma unroll
      for (int j = 0; j < 4; ++j) {
        const int col = nt * BN + wn + j * 16 + l15;
        float v = acc[i][j][reg] + b1[e * NH + col];
        v = 0.5f * v * (1.0f + erff(v * 0.70710678118654752f));
        hrow[col] = f2bf(v);
      }
    }
  }
}

// ---------------- GEMM2: contrib[slot] = h[slot] @ w2[e]^T + b2[e] (fp32) ----------------
__global__ __launch_bounds__(256, 2) void gemm2_kernel(
    const unsigned short* __restrict__ h, const float* __restrict__ w2,
    const float* __restrict__ b2, const int* __restrict__ counts,
    const int* __restrict__ list, float* __restrict__ contrib) {
  int mt, ent;
  decode_bid(blockIdx.x, NE * NNT2, mt, ent);
  const int e  = ent >> 3;
  const int nt = ent & 7;
  const int ne = counts[e];
  if (mt * BM >= ne) return;
  const int t = threadIdx.x;

  __shared__ __align__(16) unsigned char As[BM * BK * 2];   // 16 KB
  __shared__ __align__(16) unsigned char Bs[BN * BK * 4];   // 32 KB
  __shared__ int ent_s[BM];
  if (t < BM) {
    const int idx = mt * BM + t;
    ent_s[t] = (idx < ne) ? list[e * N_TOK + idx] : -1;
  }
  __syncthreads();

  const int lane = t & 63, w = t >> 6;
  const unsigned short* aP[4];
  const float* bP[8];
  unsigned char *aL[4], *bL[8];
  {
    const int l3 = lane >> 3, c7 = lane & 7;
#pragma unroll
    for (int p = 0; p < 4; ++p) {
      const int CI = w + 4 * p;
      const int R = 8 * CI + l3;
      const int c = c7 ^ (R & 7);
      const int en = ent_s[R];
      aP[p] = h + (size_t)(en >= 0 ? en : 0) * NH + c * 8;
      aL[p] = As + CI * 1024;
    }
    const int l4 = lane >> 4, c15 = lane & 15;
    const float* bbase = w2 + ((size_t)e * NO + (size_t)nt * BN) * NH;
#pragma unroll
    for (int q = 0; q < 8; ++q) {
      const int CI = w + 4 * q;
      const int R = 4 * CI + l4;
      const int c = c15 ^ (R & 15);
      bP[q] = bbase + (size_t)R * NH + c * 4;
      bL[q] = Bs + CI * 1024;
    }
  }

  const int wm = (w & 1) * 64, wn = (w >> 1) * 64;
  const int l15 = lane & 15, quad = lane >> 4;

  f32x4 acc[4][4];
#pragma unroll
  for (int i = 0; i < 4; ++i)
#pragma unroll
    for (int j = 0; j < 4; ++j) acc[i][j] = (f32x4){0.f, 0.f, 0.f, 0.f};

  for (int k0 = 0; k0 < NH; k0 += BK) {
#pragma unroll
    for (int p = 0; p < 4; ++p) glds16(aP[p] + k0, aL[p]);
#pragma unroll
    for (int q = 0; q < 8; ++q) glds16(bP[q] + k0, bL[q]);
    __syncthreads();
#pragma unroll
    for (int kk = 0; kk < BK; kk += 32) {
      short8 af[4], bfr[4];
#pragma unroll
      for (int i = 0; i < 4; ++i) {
        const int R = wm + i * 16 + l15;
        const int c0 = (kk >> 3) + quad;
        af[i] = *(const short8*)(As + R * 128 + ((c0 ^ (R & 7)) << 4));
      }
#pragma unroll
      for (int j = 0; j < 4; ++j) {
        const int R = wn + j * 16 + l15;
        const int c0 = (kk >> 2) + 2 * quad;
        const float4 f0 = *(const float4*)(Bs + R * 256 + ((c0 ^ (R & 15)) << 4));
        const float4 f1 = *(const float4*)(Bs + R * 256 + (((c0 + 1) ^ (R & 15)) << 4));
        bfr[j] = cvt8(f0, f1);
      }
#pragma unroll
      for (int i = 0; i < 4; ++i)
#pragma unroll
        for (int j = 0; j < 4; ++j)
          acc[i][j] = __builtin_amdgcn_mfma_f32_16x16x32_bf16(af[i], bfr[j], acc[i][j], 0, 0, 0);
    }
    lds_barrier();
  }

  const int r4 = quad * 4;
#pragma unroll
  for (int i = 0; i < 4; ++i) {
#pragma unroll
    for (int reg = 0; reg < 4; ++reg) {
      const int row = wm + i * 16 + r4 + reg;
      const int en = ent_s[row];
      if (en < 0) continue;
      float* crow = contrib + (size_t)en * NO;
#pragma unroll
      for (int j = 0; j < 4; ++j) {
        const int col = nt * BN + wn + j * 16 + l15;
        crow[col] = acc[i][j][reg] + b2[e * NO + col];
      }
    }
  }
}

// ---------------- Combine ----------------
__global__ __launch_bounds__(256) void combine_kernel(
    const float* __restrict__ contrib, const float* __restrict__ tkw,
    float* __restrict__ out) {
  const int gid = blockIdx.x * 256 + threadIdx.x;
  const int n = gid >> 8;
  const int c = (gid & 255) * 4;
  const float w0 = tkw[n * 2], w1 = tkw[n * 2 + 1];
  const float4 a = *(const float4*)(contrib + (size_t)(n * 2) * NO + c);
  const float4 b = *(const float4*)(contrib + (size_t)(n * 2 + 1) * NO + c);
  float4 o;
  o.x = w0 * a.x + w1 * b.x; o.y = w0 * a.y + w1 * b.y;
  o.z = w0 * a.z + w1 * b.z; o.w = w0 * a.w + w1 * b.w;
  *(float4*)(out + (size_t)n * NO + c) = o;
}

extern "C" void kernel_launch(void* const* d_in, const int* in_sizes, int n_in,
                              void* d_out, int out_size, void* d_ws, size_t ws_size,
                              hipStream_t stream) {
  const float* z  = (const float*)d_in[0];
  const float* rw = (const float*)d_in[1];
  const float* rb = (const float*)d_in[2];
  const float* w1 = (const float*)d_in[3];
  const float* b1 = (const float*)d_in[4];
  const float* w2 = (const float*)d_in[5];
  const float* b2 = (const float*)d_in[6];
  float* out = (float*)d_out;

  char* ws = (char*)d_ws;
  int*   counts = (int*)ws;                                    // 256 B
  int*   list   = (int*)(ws + 256);                            // 128 KB
  float* tkw    = (float*)(ws + 256 + 131072);                 // 16 KB
  unsigned short* zbf = (unsigned short*)(ws + 262144);        // 4 MB
  unsigned short* h = (unsigned short*)(ws + 262144 + 4194304);        // 16 MB
  float* contrib = (float*)(ws + 262144 + 4194304 + 16777216);         // 16 MB

  hipMemsetAsync(counts, 0, NE * sizeof(int), stream);
  convert_z_kernel<<<(N_TOK * DIM / 8) / 256, 256, 0, stream>>>(z, zbf);
  router_kernel<<<N_TOK, 256, 0, stream>>>(z, rw, rb, counts, list, tkw);
  gemm1_kernel<<<MT_LEVELS * NE * NNT1, 256, 0, stream>>>(zbf, w1, b1, counts, list, h);
  gemm2_kernel<<<MT_LEVELS * NE * NNT2, 256, 0, stream>>>(h, w2, b2, counts, list, contrib);
  combine_kernel<<<(N_TOK * (NO / 4)) / 256, 256, 0, stream>>>(contrib, tkw, out);
}